// Round 3
// baseline (286.664 us; speedup 1.0000x reference)
//
#include <hip/hip_runtime.h>
#include <math.h>

#define B_   32
#define C_   1024
#define N_   784
#define NF4  196          // N_/4 float4 per row
#define TD   768
#define AD   256
#define RED_ 64
#define OUT0 25690112     // B*C*H*W
#define ROWS (B_*C_)      // 32768
#define CH_  32           // score chunks (32 channels each) -> 1024 blocks
#define CPB  32           // channels per block in k_scores

typedef float f4 __attribute__((ext_vector_type(4)));   // NT-store-compatible

// workspace layout (float offsets)
#define OFF_AVG  0
#define OFF_MAX  32768
#define OFF_CA   65536
#define OFF_Q    98304    // B*AD = 8192
#define OFF_HS   106496   // B*RED = 2048
#define OFF_WVO  108544   // 1024
#define OFF_GQ   109568   // B*C = 32768
#define OFF_SV   142336   // 32
#define OFF_CNT  142368   // 32 ints
#define OFF_PS   142400   // B*CH_*N = 802816
#define OFF_PY   945216   // B*CH_*N = 802816  -> total ~7.0 MB

// ------- K1: per-row avg & max (2 rows/wave) + q proj + cnt zero -------------
__global__ void k_avgmax(const float* __restrict__ x, const float* __restrict__ text,
                         const float* __restrict__ wq, float* __restrict__ avg,
                         float* __restrict__ mx, float* __restrict__ q,
                         int* __restrict__ cnt) {
    int blk = blockIdx.x;
    int wave = threadIdx.x >> 6, lane = threadIdx.x & 63;
    if (blk < 4096) {
        int row0 = blk * 8 + wave * 2;
        const float4* r0 = (const float4*)(x + (size_t)row0 * N_);
        const float4* r1 = r0 + NF4;
        float s0 = 0.f, s1 = 0.f, m0 = -3.4e38f, m1 = -3.4e38f;
        #pragma unroll
        for (int j = 0; j < 3; ++j) {
            int i = lane + 64 * j;
            float4 v0 = r0[i], v1 = r1[i];
            s0 += v0.x + v0.y + v0.z + v0.w;
            s1 += v1.x + v1.y + v1.z + v1.w;
            m0 = fmaxf(m0, fmaxf(fmaxf(v0.x, v0.y), fmaxf(v0.z, v0.w)));
            m1 = fmaxf(m1, fmaxf(fmaxf(v1.x, v1.y), fmaxf(v1.z, v1.w)));
        }
        if (lane < 4) {
            float4 v0 = r0[192 + lane], v1 = r1[192 + lane];
            s0 += v0.x + v0.y + v0.z + v0.w;
            s1 += v1.x + v1.y + v1.z + v1.w;
            m0 = fmaxf(m0, fmaxf(fmaxf(v0.x, v0.y), fmaxf(v0.z, v0.w)));
            m1 = fmaxf(m1, fmaxf(fmaxf(v1.x, v1.y), fmaxf(v1.z, v1.w)));
        }
        for (int o = 32; o; o >>= 1) {
            s0 += __shfl_down(s0, o, 64);
            s1 += __shfl_down(s1, o, 64);
            m0 = fmaxf(m0, __shfl_down(m0, o, 64));
            m1 = fmaxf(m1, __shfl_down(m1, o, 64));
        }
        if (lane == 0) {
            avg[row0]     = s0 * (1.f / (float)N_); mx[row0]     = m0;
            avg[row0 + 1] = s1 * (1.f / (float)N_); mx[row0 + 1] = m1;
        }
    } else if (blk < 6144) {
        int w = (blk - 4096) * 4 + wave;  // 0..8191
        int b = w >> 8, a = w & 255;
        const float4* tb = (const float4*)(text + (size_t)b * TD);   // 192 f4
        const float4* wr = (const float4*)(wq + (size_t)a * TD);
        float acc = 0.f;
        #pragma unroll
        for (int j = 0; j < 3; ++j) {
            int i = lane + 64 * j;
            float4 tv = tb[i], wvv = wr[i];
            acc += tv.x * wvv.x + tv.y * wvv.y + tv.z * wvv.z + tv.w * wvv.w;
        }
        for (int o = 32; o; o >>= 1) acc += __shfl_down(acc, o, 64);
        if (lane == 0) q[(size_t)b * AD + a] = acc;
    } else {
        if (threadIdx.x < B_) cnt[threadIdx.x] = 0;
    }
}

// ---------------- K2: hs, gq = q.wk, wvo ------------------------------------
__global__ void k_proj(const float* __restrict__ avg, const float* __restrict__ mx,
                       const float* __restrict__ w1, const float* __restrict__ q,
                       const float* __restrict__ wk, const float* __restrict__ wv,
                       const float* __restrict__ wo, float* __restrict__ hs,
                       float* __restrict__ gq, float* __restrict__ wvo) {
    int blk  = blockIdx.x;
    int wave = threadIdx.x >> 6, lane = threadIdx.x & 63;
    int t = threadIdx.x;
    __shared__ float red[256];
    __shared__ float qs[AD];
    if (blk < 512) {
        int w = blk * 4 + wave;           // 0..2047
        int b = w >> 6, r = w & 63;
        const float4* av = (const float4*)(avg + (size_t)b * C_);    // 256 f4
        const float4* mv = (const float4*)(mx + (size_t)b * C_);
        const float4* wr = (const float4*)(w1 + (size_t)r * C_);
        float aa = 0.f, am = 0.f;
        #pragma unroll
        for (int j = 0; j < 4; ++j) {
            int i = lane + 64 * j;
            float4 wvv = wr[i], a4 = av[i], m4 = mv[i];
            aa += wvv.x * a4.x + wvv.y * a4.y + wvv.z * a4.z + wvv.w * a4.w;
            am += wvv.x * m4.x + wvv.y * m4.y + wvv.z * m4.z + wvv.w * m4.w;
        }
        for (int o = 32; o; o >>= 1) {
            aa += __shfl_down(aa, o, 64);
            am += __shfl_down(am, o, 64);
        }
        if (lane == 0) hs[(size_t)b * RED_ + r] = fmaxf(aa, 0.f) + fmaxf(am, 0.f);
    } else if (blk < 1024) {
        // gq[b,c] = sum_a q[b,a] * wk[a,c]; 16 blocks per b, 64 c each
        int local = blk - 512;
        int b  = local >> 4, cb = local & 15;
        int cl = t & 63, sl = t >> 6;
        int c  = cb * 64 + cl;
        qs[t] = q[(size_t)b * AD + t];
        __syncthreads();
        const float* wkp = wk + (size_t)(sl * 64) * C_ + c;
        float acc = 0.f;
        #pragma unroll 8
        for (int a = 0; a < 64; ++a) acc += qs[sl * 64 + a] * wkp[(size_t)a * C_];
        red[t] = acc;
        __syncthreads();
        if (t < 64) gq[(size_t)b * C_ + c] = red[t] + red[64 + t] + red[128 + t] + red[192 + t];
    } else {
        // wvo[c] = sum_a wo[a]*wv[a,c]; 16 blocks x 64 channels, a-loop split 4 ways
        int local = blk - 1024;
        int cl = t & 63, sl = t >> 6;
        int c = local * 64 + cl;
        const float* wvp = wv + (size_t)(sl * 64) * C_ + c;
        float acc = 0.f;
        #pragma unroll 8
        for (int a = 0; a < 64; ++a) acc += wo[sl * 64 + a] * wvp[(size_t)a * C_];
        red[t] = acc;
        __syncthreads();
        if (t < 64) wvo[local * 64 + t] = red[t] + red[64 + t] + red[128 + t] + red[192 + t];
    }
}

// ---- K3: ca + dual contraction (scores,y) + last-block softmax+sv -----------
__global__ __launch_bounds__(256) void k_scores(
        const float* __restrict__ x, const float* __restrict__ hs,
        const float* __restrict__ w2, const float* __restrict__ gq,
        const float* __restrict__ wvo,
        float* __restrict__ ca, float* __restrict__ partS, float* __restrict__ partY,
        int* __restrict__ cnt, float* __restrict__ sv) {
    int chunk = blockIdx.x, b = blockIdx.y, t = threadIdx.x;
    int wave = t >> 6, lane = t & 63;
    __shared__ float hss[RED_];
    __shared__ float redB[256];
    __shared__ float gsg[CPB], gsh[CPB];
    __shared__ float4 l4s[4 * NF4], l4y[4 * NF4];
    __shared__ float rm[4], rs[4], rd[4];
    __shared__ int winflag;

    if (t < RED_) hss[t] = hs[(size_t)b * RED_ + t];
    __syncthreads();
    // phase A: ca + per-channel weights for this block's 32 channels (64-dot only)
    {
        int cl = t & 31, sl = t >> 5;       // 8 slices x 8 r
        int c  = chunk * CPB + cl;
        const float* w2p = w2 + (size_t)c * RED_ + sl * 8;
        float a1 = 0.f;
        #pragma unroll
        for (int r = 0; r < 8; ++r) a1 += hss[sl * 8 + r] * w2p[r];
        redB[t] = a1;
    }
    __syncthreads();
    if (t < CPB) {
        float s1 = 0.f;
        #pragma unroll
        for (int k = 0; k < 8; ++k) s1 += redB[k * 32 + t];
        float cav = 1.f / (1.f + __expf(-s1));
        int c = chunk * CPB + t;
        ca[(size_t)b * C_ + c] = cav;
        gsg[t] = gq[(size_t)b * C_ + c] * cav * 0.0625f;  // scores weight
        gsh[t] = wvo[c] * cav;                            // y weight
    }
    __syncthreads();
    // phase B: one pass over x chunk, two weighted accumulations (8 ch/wave)
    const float4* xb4 = (const float4*)(x +
        ((size_t)b * C_ + (size_t)chunk * CPB + (size_t)wave * 8) * N_);
    float4 z = make_float4(0.f, 0.f, 0.f, 0.f);
    float4 s0 = z, s1v = z, s2v = z, s3 = z;
    float4 y0 = z, y1 = z, y2 = z, y3 = z;
    #pragma unroll 4
    for (int cc = 0; cc < 8; ++cc) {
        float gv = gsg[wave * 8 + cc], hv = gsh[wave * 8 + cc];
        const float4* row = xb4 + (size_t)cc * NF4;
        float4 v;
        v = row[lane];
        s0.x += gv*v.x; s0.y += gv*v.y; s0.z += gv*v.z; s0.w += gv*v.w;
        y0.x += hv*v.x; y0.y += hv*v.y; y0.z += hv*v.z; y0.w += hv*v.w;
        v = row[lane + 64];
        s1v.x += gv*v.x; s1v.y += gv*v.y; s1v.z += gv*v.z; s1v.w += gv*v.w;
        y1.x  += hv*v.x; y1.y  += hv*v.y; y1.z  += hv*v.z; y1.w  += hv*v.w;
        v = row[lane + 128];
        s2v.x += gv*v.x; s2v.y += gv*v.y; s2v.z += gv*v.z; s2v.w += gv*v.w;
        y2.x  += hv*v.x; y2.y  += hv*v.y; y2.z  += hv*v.z; y2.w  += hv*v.w;
        if (lane < 4) {
            v = row[lane + 192];
            s3.x += gv*v.x; s3.y += gv*v.y; s3.z += gv*v.z; s3.w += gv*v.w;
            y3.x += hv*v.x; y3.y += hv*v.y; y3.z += hv*v.z; y3.w += hv*v.w;
        }
    }
    l4s[wave * NF4 + lane]       = s0;
    l4s[wave * NF4 + lane + 64]  = s1v;
    l4s[wave * NF4 + lane + 128] = s2v;
    l4y[wave * NF4 + lane]       = y0;
    l4y[wave * NF4 + lane + 64]  = y1;
    l4y[wave * NF4 + lane + 128] = y2;
    if (lane < 4) {
        l4s[wave * NF4 + lane + 192] = s3;
        l4y[wave * NF4 + lane + 192] = y3;
    }
    __syncthreads();
    if (t < NF4) {
        float4 a = l4s[t], bb = l4s[NF4 + t], c4 = l4s[2 * NF4 + t], d = l4s[3 * NF4 + t];
        float4 r;
        r.x = a.x + bb.x + c4.x + d.x; r.y = a.y + bb.y + c4.y + d.y;
        r.z = a.z + bb.z + c4.z + d.z; r.w = a.w + bb.w + c4.w + d.w;
        ((float4*)(partS + ((size_t)b * CH_ + chunk) * N_))[t] = r;
        a = l4y[t]; bb = l4y[NF4 + t]; c4 = l4y[2 * NF4 + t]; d = l4y[3 * NF4 + t];
        r.x = a.x + bb.x + c4.x + d.x; r.y = a.y + bb.y + c4.y + d.y;
        r.z = a.z + bb.z + c4.z + d.z; r.w = a.w + bb.w + c4.w + d.w;
        ((float4*)(partY + ((size_t)b * CH_ + chunk) * N_))[t] = r;
    }
    __syncthreads();
    if (t == 0) {
        __threadfence();
        winflag = (atomicAdd(&cnt[b], 1) == CH_ - 1) ? 1 : 0;
    }
    __syncthreads();
    if (!winflag) return;
    __threadfence();
    // winner block: reduce CH_ partials, softmax, sv = sigmoid(attn . y)
    const float* pS = partS + (size_t)b * CH_ * N_;
    const float* pY = partY + (size_t)b * CH_ * N_;
    float v0 = 0.f, v1 = 0.f, v2 = 0.f, v3 = 0.f;
    float w0 = 0.f, w1v = 0.f, w2v = 0.f, w3 = 0.f;
    for (int ch = 0; ch < CH_; ++ch) {
        const float* pcs = pS + (size_t)ch * N_;
        const float* pcy = pY + (size_t)ch * N_;
        v0 += pcs[t]; v1 += pcs[t + 256]; v2 += pcs[t + 512];
        w0 += pcy[t]; w1v += pcy[t + 256]; w2v += pcy[t + 512];
        if (t < 16) { v3 += pcs[t + 768]; w3 += pcy[t + 768]; }
    }
    float m = fmaxf(fmaxf(v0, v1), v2);
    if (t < 16) m = fmaxf(m, v3);
    for (int o = 32; o; o >>= 1) m = fmaxf(m, __shfl_down(m, o, 64));
    if (lane == 0) rm[wave] = m;
    __syncthreads();
    float M = fmaxf(fmaxf(rm[0], rm[1]), fmaxf(rm[2], rm[3]));
    float e0 = __expf(v0 - M), e1 = __expf(v1 - M), e2 = __expf(v2 - M);
    float e3 = (t < 16) ? __expf(v3 - M) : 0.f;
    float ssum = e0 + e1 + e2 + e3;
    float dot  = e0 * w0 + e1 * w1v + e2 * w2v + e3 * w3;
    for (int o = 32; o; o >>= 1) {
        ssum += __shfl_down(ssum, o, 64);
        dot  += __shfl_down(dot,  o, 64);
    }
    if (lane == 0) { rs[wave] = ssum; rd[wave] = dot; }
    __syncthreads();
    if (t == 0) {
        float S = rs[0] + rs[1] + rs[2] + rs[3];
        float D = rd[0] + rd[1] + rd[2] + rd[3];
        sv[b] = 1.f / (1.f + __expf(-D / S));
    }
}

// ---------------- K4: out0 = x*ca*s (NT stores) ; out1 = broadcast -----------
__global__ void k_finalize(const float* __restrict__ x, const float* __restrict__ chattn,
                           const float* __restrict__ s, float* __restrict__ out) {
    int blk = blockIdx.x;
    if (blk < ROWS / 8) {
        int wave = threadIdx.x >> 6, lane = threadIdx.x & 63;
        int row0 = blk * 8 + wave * 2;
        int b    = row0 >> 10;
        float sb  = s[b];
        float sc0 = chattn[row0] * sb;
        float sc1 = chattn[row0 + 1] * sb;
        const float4* r0 = (const float4*)(x + (size_t)row0 * N_);
        const float4* r1 = r0 + NF4;
        f4* o0 = (f4*)(out + (size_t)row0 * N_);
        f4* o1 = o0 + NF4;
        #pragma unroll
        for (int j = 0; j < 3; ++j) {
            int i = lane + 64 * j;
            float4 v0 = r0[i], v1 = r1[i];
            f4 w0 = { v0.x * sc0, v0.y * sc0, v0.z * sc0, v0.w * sc0 };
            f4 w1 = { v1.x * sc1, v1.y * sc1, v1.z * sc1, v1.w * sc1 };
            __builtin_nontemporal_store(w0, &o0[i]);
            __builtin_nontemporal_store(w1, &o1[i]);
        }
        if (lane < 4) {
            int i = 192 + lane;
            float4 v0 = r0[i], v1 = r1[i];
            f4 w0 = { v0.x * sc0, v0.y * sc0, v0.z * sc0, v0.w * sc0 };
            f4 w1 = { v1.x * sc1, v1.y * sc1, v1.z * sc1, v1.w * sc1 };
            __builtin_nontemporal_store(w0, &o0[i]);
            __builtin_nontemporal_store(w1, &o1[i]);
        }
    } else {
        int idx = (blk - ROWS / 8) * 256 + threadIdx.x;  // float4 index into out1
        if (idx < (B_ * N_) / 4) {
            int b = idx / (N_ / 4);
            float v = s[b];
            f4 vv = { v, v, v, v };
            __builtin_nontemporal_store(vv, &((f4*)(out + OUT0))[idx]);
        }
    }
}

extern "C" void kernel_launch(void* const* d_in, const int* in_sizes, int n_in,
                              void* d_out, int out_size, void* d_ws, size_t ws_size,
                              hipStream_t stream) {
    const float* x    = (const float*)d_in[0];
    const float* text = (const float*)d_in[1];
    const float* w1   = (const float*)d_in[2];
    const float* w2   = (const float*)d_in[3];
    const float* wq   = (const float*)d_in[4];
    const float* wk   = (const float*)d_in[5];
    const float* wv   = (const float*)d_in[6];
    const float* wo   = (const float*)d_in[7];
    float* out = (float*)d_out;
    float* ws  = (float*)d_ws;

    float* avg   = ws + OFF_AVG;
    float* mx    = ws + OFF_MAX;
    float* ca    = ws + OFF_CA;
    float* q     = ws + OFF_Q;
    float* hs    = ws + OFF_HS;
    float* wvo   = ws + OFF_WVO;
    float* gq    = ws + OFF_GQ;
    float* sv    = ws + OFF_SV;
    int*   cnt   = (int*)(ws + OFF_CNT);
    float* partS = ws + OFF_PS;
    float* partY = ws + OFF_PY;

    k_avgmax<<<6145, 256, 0, stream>>>(x, text, wq, avg, mx, q, cnt);
    k_proj<<<1040, 256, 0, stream>>>(avg, mx, w1, q, wk, wv, wo, hs, gq, wvo);
    k_scores<<<dim3(CH_, B_), 256, 0, stream>>>(x, hs, w2, gq, wvo, ca, partS, partY, cnt, sv);
    k_finalize<<<ROWS / 8 + 25, 256, 0, stream>>>(x, ca, sv, out);
}

// Round 4
// 260.644 us; speedup vs baseline: 1.0998x; 1.0998x over previous
//
#include <hip/hip_runtime.h>
#include <math.h>

#define B_   32
#define C_   1024
#define N_   784
#define NF4  196          // N_/4 float4 per row
#define TD   768
#define AD   256
#define RED_ 64
#define OUT0 25690112     // B*C*H*W
#define ROWS (B_*C_)      // 32768
#define CH_  16           // score chunks (64 channels each) -> 512 blocks
#define CPB  64           // channels per block in k_scores

typedef float f4 __attribute__((ext_vector_type(4)));   // NT-store-compatible

// workspace layout (float offsets)
#define OFF_AVG  0
#define OFF_MAX  32768
#define OFF_CA   65536
#define OFF_Q    98304    // B*AD = 8192
#define OFF_HS   106496   // B*RED = 2048
#define OFF_WVO  108544   // 1024
#define OFF_GQ   109568   // B*C = 32768
#define OFF_SV   142336   // 32
#define OFF_CNT  142368   // 32 ints
#define OFF_PS   142400   // B*CH_*N = 401408
#define OFF_PY   543808   // B*CH_*N = 401408  -> total ~3.8 MB

// ------- K1: per-row avg & max (2 rows/wave) + q proj + cnt zero -------------
__global__ void k_avgmax(const float* __restrict__ x, const float* __restrict__ text,
                         const float* __restrict__ wq, float* __restrict__ avg,
                         float* __restrict__ mx, float* __restrict__ q,
                         int* __restrict__ cnt) {
    int blk = blockIdx.x;
    int wave = threadIdx.x >> 6, lane = threadIdx.x & 63;
    if (blk < 4096) {
        int row0 = blk * 8 + wave * 2;
        const float4* r0 = (const float4*)(x + (size_t)row0 * N_);
        const float4* r1 = r0 + NF4;
        float s0 = 0.f, s1 = 0.f, m0 = -3.4e38f, m1 = -3.4e38f;
        #pragma unroll
        for (int j = 0; j < 3; ++j) {
            int i = lane + 64 * j;
            float4 v0 = r0[i], v1 = r1[i];
            s0 += v0.x + v0.y + v0.z + v0.w;
            s1 += v1.x + v1.y + v1.z + v1.w;
            m0 = fmaxf(m0, fmaxf(fmaxf(v0.x, v0.y), fmaxf(v0.z, v0.w)));
            m1 = fmaxf(m1, fmaxf(fmaxf(v1.x, v1.y), fmaxf(v1.z, v1.w)));
        }
        if (lane < 4) {
            float4 v0 = r0[192 + lane], v1 = r1[192 + lane];
            s0 += v0.x + v0.y + v0.z + v0.w;
            s1 += v1.x + v1.y + v1.z + v1.w;
            m0 = fmaxf(m0, fmaxf(fmaxf(v0.x, v0.y), fmaxf(v0.z, v0.w)));
            m1 = fmaxf(m1, fmaxf(fmaxf(v1.x, v1.y), fmaxf(v1.z, v1.w)));
        }
        for (int o = 32; o; o >>= 1) {
            s0 += __shfl_down(s0, o, 64);
            s1 += __shfl_down(s1, o, 64);
            m0 = fmaxf(m0, __shfl_down(m0, o, 64));
            m1 = fmaxf(m1, __shfl_down(m1, o, 64));
        }
        if (lane == 0) {
            avg[row0]     = s0 * (1.f / (float)N_); mx[row0]     = m0;
            avg[row0 + 1] = s1 * (1.f / (float)N_); mx[row0 + 1] = m1;
        }
    } else if (blk < 6144) {
        int w = (blk - 4096) * 4 + wave;  // 0..8191
        int b = w >> 8, a = w & 255;
        const float4* tb = (const float4*)(text + (size_t)b * TD);   // 192 f4
        const float4* wr = (const float4*)(wq + (size_t)a * TD);
        float acc = 0.f;
        #pragma unroll
        for (int j = 0; j < 3; ++j) {
            int i = lane + 64 * j;
            float4 tv = tb[i], wvv = wr[i];
            acc += tv.x * wvv.x + tv.y * wvv.y + tv.z * wvv.z + tv.w * wvv.w;
        }
        for (int o = 32; o; o >>= 1) acc += __shfl_down(acc, o, 64);
        if (lane == 0) q[(size_t)b * AD + a] = acc;
    } else {
        if (threadIdx.x < B_) cnt[threadIdx.x] = 0;
    }
}

// ---------------- K2: hs, gq = q.wk, wvo ------------------------------------
__global__ void k_proj(const float* __restrict__ avg, const float* __restrict__ mx,
                       const float* __restrict__ w1, const float* __restrict__ q,
                       const float* __restrict__ wk, const float* __restrict__ wv,
                       const float* __restrict__ wo, float* __restrict__ hs,
                       float* __restrict__ gq, float* __restrict__ wvo) {
    int blk  = blockIdx.x;
    int wave = threadIdx.x >> 6, lane = threadIdx.x & 63;
    int t = threadIdx.x;
    __shared__ float red[256];
    __shared__ float qs[AD];
    if (blk < 512) {
        int w = blk * 4 + wave;           // 0..2047
        int b = w >> 6, r = w & 63;
        const float4* av = (const float4*)(avg + (size_t)b * C_);    // 256 f4
        const float4* mv = (const float4*)(mx + (size_t)b * C_);
        const float4* wr = (const float4*)(w1 + (size_t)r * C_);
        float aa = 0.f, am = 0.f;
        #pragma unroll
        for (int j = 0; j < 4; ++j) {
            int i = lane + 64 * j;
            float4 wvv = wr[i], a4 = av[i], m4 = mv[i];
            aa += wvv.x * a4.x + wvv.y * a4.y + wvv.z * a4.z + wvv.w * a4.w;
            am += wvv.x * m4.x + wvv.y * m4.y + wvv.z * m4.z + wvv.w * m4.w;
        }
        for (int o = 32; o; o >>= 1) {
            aa += __shfl_down(aa, o, 64);
            am += __shfl_down(am, o, 64);
        }
        if (lane == 0) hs[(size_t)b * RED_ + r] = fmaxf(aa, 0.f) + fmaxf(am, 0.f);
    } else if (blk < 1024) {
        // gq[b,c] = sum_a q[b,a] * wk[a,c]; 16 blocks per b, 64 c each
        int local = blk - 512;
        int b  = local >> 4, cb = local & 15;
        int cl = t & 63, sl = t >> 6;
        int c  = cb * 64 + cl;
        qs[t] = q[(size_t)b * AD + t];
        __syncthreads();
        const float* wkp = wk + (size_t)(sl * 64) * C_ + c;
        float acc = 0.f;
        #pragma unroll 8
        for (int a = 0; a < 64; ++a) acc += qs[sl * 64 + a] * wkp[(size_t)a * C_];
        red[t] = acc;
        __syncthreads();
        if (t < 64) gq[(size_t)b * C_ + c] = red[t] + red[64 + t] + red[128 + t] + red[192 + t];
    } else {
        // wvo[c] = sum_a wo[a]*wv[a,c]; 16 blocks x 64 channels, a-loop split 4 ways
        int local = blk - 1024;
        int cl = t & 63, sl = t >> 6;
        int c = local * 64 + cl;
        const float* wvp = wv + (size_t)(sl * 64) * C_ + c;
        float acc = 0.f;
        #pragma unroll 8
        for (int a = 0; a < 64; ++a) acc += wo[sl * 64 + a] * wvp[(size_t)a * C_];
        red[t] = acc;
        __syncthreads();
        if (t < 64) wvo[local * 64 + t] = red[t] + red[64 + t] + red[128 + t] + red[192 + t];
    }
}

// ---- K3: ca + dual contraction (scores,y) + last-block softmax+sv -----------
__global__ __launch_bounds__(256) void k_scores(
        const float* __restrict__ x, const float* __restrict__ hs,
        const float* __restrict__ w2, const float* __restrict__ gq,
        const float* __restrict__ wvo,
        float* __restrict__ ca, float* __restrict__ partS, float* __restrict__ partY,
        int* __restrict__ cnt, float* __restrict__ sv) {
    int chunk = blockIdx.x, b = blockIdx.y, t = threadIdx.x;
    int wave = t >> 6, lane = t & 63;
    __shared__ float hss[RED_];
    __shared__ float redB[256];
    __shared__ float gsg[CPB], gsh[CPB];
    __shared__ float4 l4s[4 * NF4], l4y[4 * NF4];
    __shared__ float rm[4], rs[4], rd[4];
    __shared__ int winflag;

    if (t < RED_) hss[t] = hs[(size_t)b * RED_ + t];
    __syncthreads();
    // phase A: ca + per-channel weights for this block's 64 channels (w2 dot only)
    {
        int cl = t & 63, sl = t >> 6;       // 4 slices x 16 r
        int c  = chunk * CPB + cl;
        const float* w2p = w2 + (size_t)c * RED_ + sl * 16;
        float a1 = 0.f;
        #pragma unroll
        for (int r = 0; r < 16; ++r) a1 += hss[sl * 16 + r] * w2p[r];
        redB[t] = a1;
    }
    __syncthreads();
    if (t < CPB) {
        float s1 = redB[t] + redB[64 + t] + redB[128 + t] + redB[192 + t];
        float cav = 1.f / (1.f + __expf(-s1));
        int c = chunk * CPB + t;
        ca[(size_t)b * C_ + c] = cav;
        gsg[t] = gq[(size_t)b * C_ + c] * cav * 0.0625f;  // scores weight
        gsh[t] = wvo[c] * cav;                            // y weight
    }
    __syncthreads();
    // phase B: one pass over x chunk, two weighted accumulations (16 ch/wave)
    const float4* xb4 = (const float4*)(x +
        ((size_t)b * C_ + (size_t)chunk * CPB + (size_t)wave * 16) * N_);
    float4 z = make_float4(0.f, 0.f, 0.f, 0.f);
    float4 s0 = z, s1v = z, s2v = z, s3 = z;
    float4 y0 = z, y1 = z, y2 = z, y3 = z;
    #pragma unroll 4
    for (int cc = 0; cc < 16; ++cc) {
        float gv = gsg[wave * 16 + cc], hv = gsh[wave * 16 + cc];
        const float4* row = xb4 + (size_t)cc * NF4;
        float4 v;
        v = row[lane];
        s0.x += gv*v.x; s0.y += gv*v.y; s0.z += gv*v.z; s0.w += gv*v.w;
        y0.x += hv*v.x; y0.y += hv*v.y; y0.z += hv*v.z; y0.w += hv*v.w;
        v = row[lane + 64];
        s1v.x += gv*v.x; s1v.y += gv*v.y; s1v.z += gv*v.z; s1v.w += gv*v.w;
        y1.x  += hv*v.x; y1.y  += hv*v.y; y1.z  += hv*v.z; y1.w  += hv*v.w;
        v = row[lane + 128];
        s2v.x += gv*v.x; s2v.y += gv*v.y; s2v.z += gv*v.z; s2v.w += gv*v.w;
        y2.x  += hv*v.x; y2.y  += hv*v.y; y2.z  += hv*v.z; y2.w  += hv*v.w;
        if (lane < 4) {
            v = row[lane + 192];
            s3.x += gv*v.x; s3.y += gv*v.y; s3.z += gv*v.z; s3.w += gv*v.w;
            y3.x += hv*v.x; y3.y += hv*v.y; y3.z += hv*v.z; y3.w += hv*v.w;
        }
    }
    l4s[wave * NF4 + lane]       = s0;
    l4s[wave * NF4 + lane + 64]  = s1v;
    l4s[wave * NF4 + lane + 128] = s2v;
    l4y[wave * NF4 + lane]       = y0;
    l4y[wave * NF4 + lane + 64]  = y1;
    l4y[wave * NF4 + lane + 128] = y2;
    if (lane < 4) {
        l4s[wave * NF4 + lane + 192] = s3;
        l4y[wave * NF4 + lane + 192] = y3;
    }
    __syncthreads();
    if (t < NF4) {
        float4 a = l4s[t], bb = l4s[NF4 + t], c4 = l4s[2 * NF4 + t], d = l4s[3 * NF4 + t];
        float4 r;
        r.x = a.x + bb.x + c4.x + d.x; r.y = a.y + bb.y + c4.y + d.y;
        r.z = a.z + bb.z + c4.z + d.z; r.w = a.w + bb.w + c4.w + d.w;
        ((float4*)(partS + ((size_t)b * CH_ + chunk) * N_))[t] = r;
        a = l4y[t]; bb = l4y[NF4 + t]; c4 = l4y[2 * NF4 + t]; d = l4y[3 * NF4 + t];
        r.x = a.x + bb.x + c4.x + d.x; r.y = a.y + bb.y + c4.y + d.y;
        r.z = a.z + bb.z + c4.z + d.z; r.w = a.w + bb.w + c4.w + d.w;
        ((float4*)(partY + ((size_t)b * CH_ + chunk) * N_))[t] = r;
    }
    __syncthreads();
    if (t == 0) {
        __threadfence();
        winflag = (atomicAdd(&cnt[b], 1) == CH_ - 1) ? 1 : 0;
    }
    __syncthreads();
    if (!winflag) return;
    __threadfence();
    // winner block: reduce CH_ partials, softmax, sv = sigmoid(attn . y)
    const float* pS = partS + (size_t)b * CH_ * N_;
    const float* pY = partY + (size_t)b * CH_ * N_;
    float v0 = 0.f, v1 = 0.f, v2 = 0.f, v3 = 0.f;
    float w0 = 0.f, w1v = 0.f, w2v = 0.f, w3 = 0.f;
    for (int ch = 0; ch < CH_; ++ch) {
        const float* pcs = pS + (size_t)ch * N_;
        const float* pcy = pY + (size_t)ch * N_;
        v0 += pcs[t]; v1 += pcs[t + 256]; v2 += pcs[t + 512];
        w0 += pcy[t]; w1v += pcy[t + 256]; w2v += pcy[t + 512];
        if (t < 16) { v3 += pcs[t + 768]; w3 += pcy[t + 768]; }
    }
    float m = fmaxf(fmaxf(v0, v1), v2);
    if (t < 16) m = fmaxf(m, v3);
    for (int o = 32; o; o >>= 1) m = fmaxf(m, __shfl_down(m, o, 64));
    if (lane == 0) rm[wave] = m;
    __syncthreads();
    float M = fmaxf(fmaxf(rm[0], rm[1]), fmaxf(rm[2], rm[3]));
    float e0 = __expf(v0 - M), e1 = __expf(v1 - M), e2 = __expf(v2 - M);
    float e3 = (t < 16) ? __expf(v3 - M) : 0.f;
    float ssum = e0 + e1 + e2 + e3;
    float dot  = e0 * w0 + e1 * w1v + e2 * w2v + e3 * w3;
    for (int o = 32; o; o >>= 1) {
        ssum += __shfl_down(ssum, o, 64);
        dot  += __shfl_down(dot,  o, 64);
    }
    if (lane == 0) { rs[wave] = ssum; rd[wave] = dot; }
    __syncthreads();
    if (t == 0) {
        float S = rs[0] + rs[1] + rs[2] + rs[3];
        float D = rd[0] + rd[1] + rd[2] + rd[3];
        sv[b] = 1.f / (1.f + __expf(-D / S));
    }
}

// ---------------- K4: out0 = x*ca*s (NT stores) ; out1 = broadcast -----------
__global__ void k_finalize(const float* __restrict__ x, const float* __restrict__ chattn,
                           const float* __restrict__ s, float* __restrict__ out) {
    int blk = blockIdx.x;
    if (blk < ROWS / 8) {
        int wave = threadIdx.x >> 6, lane = threadIdx.x & 63;
        int row0 = blk * 8 + wave * 2;
        int b    = row0 >> 10;
        float sb  = s[b];
        float sc0 = chattn[row0] * sb;
        float sc1 = chattn[row0 + 1] * sb;
        const float4* r0 = (const float4*)(x + (size_t)row0 * N_);
        const float4* r1 = r0 + NF4;
        f4* o0 = (f4*)(out + (size_t)row0 * N_);
        f4* o1 = o0 + NF4;
        #pragma unroll
        for (int j = 0; j < 3; ++j) {
            int i = lane + 64 * j;
            float4 v0 = r0[i], v1 = r1[i];
            f4 w0 = { v0.x * sc0, v0.y * sc0, v0.z * sc0, v0.w * sc0 };
            f4 w1 = { v1.x * sc1, v1.y * sc1, v1.z * sc1, v1.w * sc1 };
            __builtin_nontemporal_store(w0, &o0[i]);
            __builtin_nontemporal_store(w1, &o1[i]);
        }
        if (lane < 4) {
            int i = 192 + lane;
            float4 v0 = r0[i], v1 = r1[i];
            f4 w0 = { v0.x * sc0, v0.y * sc0, v0.z * sc0, v0.w * sc0 };
            f4 w1 = { v1.x * sc1, v1.y * sc1, v1.z * sc1, v1.w * sc1 };
            __builtin_nontemporal_store(w0, &o0[i]);
            __builtin_nontemporal_store(w1, &o1[i]);
        }
    } else {
        int idx = (blk - ROWS / 8) * 256 + threadIdx.x;  // float4 index into out1
        if (idx < (B_ * N_) / 4) {
            int b = idx / (N_ / 4);
            float v = s[b];
            f4 vv = { v, v, v, v };
            __builtin_nontemporal_store(vv, &((f4*)(out + OUT0))[idx]);
        }
    }
}

extern "C" void kernel_launch(void* const* d_in, const int* in_sizes, int n_in,
                              void* d_out, int out_size, void* d_ws, size_t ws_size,
                              hipStream_t stream) {
    const float* x    = (const float*)d_in[0];
    const float* text = (const float*)d_in[1];
    const float* w1   = (const float*)d_in[2];
    const float* w2   = (const float*)d_in[3];
    const float* wq   = (const float*)d_in[4];
    const float* wk   = (const float*)d_in[5];
    const float* wv   = (const float*)d_in[6];
    const float* wo   = (const float*)d_in[7];
    float* out = (float*)d_out;
    float* ws  = (float*)d_ws;

    float* avg   = ws + OFF_AVG;
    float* mx    = ws + OFF_MAX;
    float* ca    = ws + OFF_CA;
    float* q     = ws + OFF_Q;
    float* hs    = ws + OFF_HS;
    float* wvo   = ws + OFF_WVO;
    float* gq    = ws + OFF_GQ;
    float* sv    = ws + OFF_SV;
    int*   cnt   = (int*)(ws + OFF_CNT);
    float* partS = ws + OFF_PS;
    float* partY = ws + OFF_PY;

    k_avgmax<<<6145, 256, 0, stream>>>(x, text, wq, avg, mx, q, cnt);
    k_proj<<<1040, 256, 0, stream>>>(avg, mx, w1, q, wk, wv, wo, hs, gq, wvo);
    k_scores<<<dim3(CH_, B_), 256, 0, stream>>>(x, hs, w2, gq, wvo, ca, partS, partY, cnt, sv);
    k_finalize<<<ROWS / 8 + 25, 256, 0, stream>>>(x, ca, sv, out);
}